// Round 10
// baseline (86.606 us; speedup 1.0000x reference)
//
#include <hip/hip_runtime.h>

#define NB    4
#define DIN_  64
#define DOUT_ 64
#define KN    16
#define NPT   8192
#define CPAD  264   // 256 c-entries + 8 pad shorts; rows 528B (16B-aligned)

typedef __attribute__((ext_vector_type(8))) short short8;
typedef __attribute__((ext_vector_type(4))) float v4f;

__device__ __forceinline__ float bf2f(unsigned short u) {
    unsigned int x = ((unsigned int)u) << 16;
    float f; __builtin_memcpy(&f, &x, 4); return f;
}
__device__ __forceinline__ unsigned short f2bf(float f) {
    unsigned int x; __builtin_memcpy(&x, &f, 4);
    x += 0x7fffu + ((x >> 16) & 1u);   // RNE
    return (unsigned short)(x >> 16);
}

// ---------- prep: 3 jobs in one dispatch, XCD-affine with k_main ----------
// HW dispatch: block i -> XCD (i&7) (m09/m157). XCD x owns batch b=x&3,
// n-half [(x>>2)*4096, +4096). k_prep writes ft/pt for exactly the slab its
// own XCD's k_main blocks gather from -> gathers hit own-XCD dirty L2.
// blocks [0,512):  feat fp32 [B][64][N] -> ft bf16 [B][N][64]
// blocks [512,640): pos fp32 [B][3][N]  -> pt float4 (x,y,z,1)
// blocks [640,648): theta/pbias -> tbs bf16, epilogue-lane-order swizzled
__global__ void k_prep(const float* __restrict__ feat, const float* __restrict__ pos,
                       const float* __restrict__ theta, const float* __restrict__ pbias,
                       unsigned short* __restrict__ ft, float4* __restrict__ pt,
                       unsigned short* __restrict__ tbs) {
    __shared__ float tile[64][65];
    const int bid = blockIdx.x;
    if (bid < 512) {
        int xcd = bid & 7, cidx = bid >> 3;          // cidx 0..63
        int b = xcd & 3;
        int n0 = (((xcd >> 2) << 6) + cidx) << 6;    // (half*64 + cidx)*64
        int lane = threadIdx.x & 63, w = threadIdx.x >> 6;
#pragma unroll
        for (int r = 0; r < 16; ++r) {
            int i = (r << 2) | w;
            tile[i][lane] = feat[(b*DIN_ + i)*NPT + n0 + lane];
        }
        __syncthreads();
#pragma unroll
        for (int r = 0; r < 16; ++r) {
            int n = (r << 2) | w;
            ft[((size_t)(b*NPT + n0 + n))*DIN_ + lane] = f2bf(tile[lane][n]);
        }
    } else if (bid < 640) {
        int pb  = bid - 512;                         // 0..127
        int xcd = pb & 7, idx = pb >> 3;             // idx 0..15
        int b   = xcd & 3;
        int n   = (((xcd >> 2) << 12) + (idx << 8)) + threadIdx.x;
        float4 v;
        v.x = pos[(b*3 + 0)*NPT + n];
        v.y = pos[(b*3 + 1)*NPT + n];
        v.z = pos[(b*3 + 2)*NPT + n];
        v.w = 1.0f;
        pt[b*NPT + n] = v;
    } else {
        int e = (bid - 640)*256 + threadIdx.x;   // 0..2047 = [w][ks][lane]
        int w  = e >> 9;
        int ks = (e >> 6) & 7;
        int ln = e & 63;
        int orow = (w << 4) + (ln & 15);
        int koff = (ks << 5) + ((ln >> 4) << 3);
        short8 u;
#pragma unroll
        for (int j = 0; j < 8; ++j) {
            int c = koff + j;
            float v = (c < 192) ? theta[c*64 + orow] : pbias[(c - 192)*64 + orow];
            u[j] = (short)f2bf(v);
        }
        *reinterpret_cast<short8*>(tbs + (size_t)e*8) = u;   // 16B aligned
    }
}

// ---------- main: R8 structure + matching XCD affinity + sibling L2 sweep ----------
template<bool USE_WS>
__global__ __launch_bounds__(256, 4) void k_main(
    const float*          __restrict__ feat,
    const float*          __restrict__ pos,
    const int*            __restrict__ nbr,
    const float*          __restrict__ theta,
    const float*          __restrict__ pbias,
    const float*          __restrict__ fbias,
    const unsigned short* __restrict__ ft,
    const float4*         __restrict__ pt,
    const unsigned short* __restrict__ tbs,
    float*                __restrict__ out)
{
    __shared__ __align__(16) unsigned short Xt[32*CPAD];  // 16896 B  [q][c]
    __shared__ int    nbs[KN*32];                         // 2048 B   [k][q]
    __shared__ float4 pcs[32];                            // 512 B
    __shared__ float4 ptk[32][16];                        // 8192 B   [q][k]
    __shared__ __align__(16) float out_s[64][32];         // 8192 B   [o][n]
    // total 35840 B -> 4 blocks/CU

    const int tid  = threadIdx.x;
    const int lane = tid & 63;
    const int w    = tid >> 6;
    const int j16  = lane & 15;
    const int pt2  = lane >> 4;    // stage1: which of 4 points; epilogue: quad (kg)

    // XCD-affine mapping, matched to k_prep: XCD x -> batch x&3, half x>>2.
    const int bid   = blockIdx.x;
    const int xcd   = bid & 7;
    const int cidx  = bid >> 3;                  // 0..127
    const int b     = xcd & 3;
    const int half  = xcd >> 2;
    const int nb0   = (((half << 7) + cidx) << 5) & 8191;   // chunk*32

    const unsigned short* ftb = ft + (((size_t)b) << 19);   // b*NPT*64
    const float4*         ptb = pt + b*NPT;

    // ---- sibling-half L2 warm sweep (issue first; sunk after preamble) ----
    // Sibling XCD wrote ft/pt rows [sib0, sib0+4096) dirty in ITS L2. Bulk-read
    // our 4KB ft slice + 512B pt slice once -> lines migrate to own L2 clean,
    // instead of ~1000cy cross-XCD snoops per gather.
    float4 s0 = make_float4(0.f,0.f,0.f,0.f), s1 = s0;
    if (USE_WS) {
        const int sib0 = (half ^ 1) << 12;
        const float4* swf = reinterpret_cast<const float4*>(
            ftb + ((size_t)(sib0 + (cidx << 5)) << 6));      // 32 rows x 128B
        s0 = swf[tid];                                       // 256 x 16B = 4KB
        if (tid < 32) s1 = ptb[sib0 + (cidx << 5) + tid];    // 32 x 16B
    }

    // ---- cooperative preamble: nbr slab + center positions ----
#pragma unroll
    for (int r = 0; r < 2; ++r) {
        int idx = tid + (r << 8);            // 0..511
        int k = idx >> 5, c = idx & 31;
        nbs[idx] = nbr[(b*KN + k)*NPT + nb0 + c];
    }
    if (tid < 128) {
        if (USE_WS) {
            ((float*)pcs)[tid] = ((const float*)(ptb + nb0))[tid];
        } else if (tid < 32) {
            int n = nb0 + tid;
            pcs[tid] = make_float4(pos[(b*3+0)*NPT + n], pos[(b*3+1)*NPT + n],
                                   pos[(b*3+2)*NPT + n], 1.0f);
        }
    }
    // keep sweep loads alive (rule #17); waits overlap the preamble barrier
    asm volatile("" :: "v"(s0.x), "v"(s0.w), "v"(s1.x), "v"(s1.w));
    __syncthreads();

    // ---- stage 1: 2 passes x 4 points per wave; lane owns (point, 4-feature chunk) ----
#pragma unroll
    for (int pass = 0; pass < 2; ++pass) {
        const int q = (w << 3) + (pass << 2) + pt2;
        const float4 pc = pcs[q];

        float acc[4][4];
#pragma unroll
        for (int p = 0; p < 4; ++p)
#pragma unroll
            for (int j = 0; j < 4; ++j) acc[p][j] = 0.f;

        if (USE_WS) {
            // pt dedup (R6): lane (pt2 -> q, j16 -> k) loads pt once.
            const int idp = nbs[(j16 << 5) + q];
            ptk[q][j16] = ptb[idp];

            // depth-16 gather pipeline (R7): all ft loads issued before any FMA.
            ushort4 frA[8], frB[8];
#pragma unroll
            for (int k = 0; k < 8; ++k) {
                const int id = nbs[(k << 5) + q];
                frA[k] = *reinterpret_cast<const ushort4*>(
                    ftb + (((size_t)id) << 6) + (j16 << 2));
            }
#pragma unroll
            for (int k = 0; k < 8; ++k) {
                const int id = nbs[((k + 8) << 5) + q];
                frB[k] = *reinterpret_cast<const ushort4*>(
                    ftb + (((size_t)id) << 6) + (j16 << 2));
            }
#pragma unroll
            for (int k = 0; k < 8; ++k) {
                const float4 pg = ptk[q][k];
                float f[4] = { bf2f(frA[k].x), bf2f(frA[k].y),
                               bf2f(frA[k].z), bf2f(frA[k].w) };
#pragma unroll
                for (int j = 0; j < 4; ++j) {
                    acc[0][j] += pg.x * f[j];
                    acc[1][j] += pg.y * f[j];
                    acc[2][j] += pg.z * f[j];
                    acc[3][j] += f[j];
                }
            }
#pragma unroll
            for (int k = 0; k < 8; ++k) {
                const float4 pg = ptk[q][k + 8];
                float f[4] = { bf2f(frB[k].x), bf2f(frB[k].y),
                               bf2f(frB[k].z), bf2f(frB[k].w) };
#pragma unroll
                for (int j = 0; j < 4; ++j) {
                    acc[0][j] += pg.x * f[j];
                    acc[1][j] += pg.y * f[j];
                    acc[2][j] += pg.z * f[j];
                    acc[3][j] += f[j];
                }
            }
        } else {
#pragma unroll 4
            for (int k = 0; k < KN; ++k) {
                const int id = nbs[(k << 5) + q];
                float4 pg; float f[4];
                pg.x = pos[(b*3+0)*NPT + id];
                pg.y = pos[(b*3+1)*NPT + id];
                pg.z = pos[(b*3+2)*NPT + id];
                pg.w = 1.0f;
#pragma unroll
                for (int j = 0; j < 4; ++j)
                    f[j] = feat[(b*DIN_ + (j16<<2) + j)*NPT + id];
#pragma unroll
                for (int j = 0; j < 4; ++j) {
                    acc[0][j] += pg.x * f[j];
                    acc[1][j] += pg.y * f[j];
                    acc[2][j] += pg.z * f[j];
                    acc[3][j] += f[j];
                }
            }
        }
        // center correction: M_p -= pc_p * S
#pragma unroll
        for (int j = 0; j < 4; ++j) {
            acc[0][j] -= pc.x * acc[3][j];
            acc[1][j] -= pc.y * acc[3][j];
            acc[2][j] -= pc.z * acc[3][j];
        }
        // write X[q][c], c = p*64 + j16*4 + j  (bf16)
#pragma unroll
        for (int p = 0; p < 4; ++p) {
            ushort4 pk;
            pk.x = f2bf(acc[p][0]); pk.y = f2bf(acc[p][1]);
            pk.z = f2bf(acc[p][2]); pk.w = f2bf(acc[p][3]);
            *reinterpret_cast<ushort4*>(&Xt[q*CPAD + (p<<6) + (j16<<2)]) = pk;
        }
    }
    __syncthreads();

    // ---- epilogue: wave w -> o-rows [16w,16w+16); A-frags from swizzled tbs ----
    const int kg   = pt2;                 // mfma quad
    const int orow = (w << 4) + j16;      // A: m = lane&15
    v4f acc0 = {0.f,0.f,0.f,0.f}, acc1 = {0.f,0.f,0.f,0.f};
#pragma unroll
    for (int ks = 0; ks < 8; ++ks) {
        const int koff = (ks << 5) + (kg << 3);   // k = quad*8 + j
        short8 a;
        if (USE_WS) {
            // contiguous: 64 lanes x 16B = 1KB segment per inst
            a = *reinterpret_cast<const short8*>(
                tbs + ((size_t)(((w << 3) + ks) << 6) + lane) * 8);
        } else {
#pragma unroll
            for (int j = 0; j < 8; ++j) {
                int c = koff + j;
                float v = (c < 192) ? theta[c*64 + orow] : pbias[(c - 192)*64 + orow];
                a[j] = (short)f2bf(v);
            }
        }
        short8 b0 = *reinterpret_cast<const short8*>(&Xt[j16*CPAD + koff]);
        short8 b1 = *reinterpret_cast<const short8*>(&Xt[(16 + j16)*CPAD + koff]);
        acc0 = __builtin_amdgcn_mfma_f32_16x16x32_bf16(a, b0, acc0, 0, 0, 0);
        acc1 = __builtin_amdgcn_mfma_f32_16x16x32_bf16(a, b1, acc1, 0, 0, 0);
    }
    // C/D: col=lane&15 (point), row=quad*4+reg (o). Stage to LDS, then write
    // FULL 128B lines (one o-row's 32 floats = one cache line) -> no RFO.
#pragma unroll
    for (int r = 0; r < 4; ++r) {
        const int o = (w << 4) + (kg << 2) + r;
        const float fb = fbias[o];
        out_s[o][j16]      = acc0[r] + fb;
        out_s[o][16 + j16] = acc1[r] + fb;
    }
    __syncthreads();
#pragma unroll
    for (int rep = 0; rep < 2; ++rep) {
        const int c  = tid + (rep << 8);     // 0..511 float4-chunks
        const int o  = c >> 3, seg = c & 7;
        const float4 v = *reinterpret_cast<const float4*>(&out_s[o][seg << 2]);
        *reinterpret_cast<float4*>(
            &out[(size_t)(b*DOUT_ + o)*NPT + nb0 + (seg << 2)]) = v;
    }
}

extern "C" void kernel_launch(void* const* d_in, const int* in_sizes, int n_in,
                              void* d_out, int out_size, void* d_ws, size_t ws_size,
                              hipStream_t stream) {
    const float* feat  = (const float*)d_in[0];
    const float* pos   = (const float*)d_in[1];
    const int*   nbr   = (const int*)d_in[2];
    const float* theta = (const float*)d_in[3];
    const float* pbias = (const float*)d_in[4];
    const float* fbias = (const float*)d_in[5];
    float* out = (float*)d_out;

    const size_t ft_bytes  = (size_t)NB*NPT*DIN_*2;          // 4 MiB
    const size_t pt_bytes  = (size_t)NB*NPT*sizeof(float4);  // 512 KiB
    const size_t tbs_bytes = (size_t)DOUT_*256*2;            // 32 KiB
    const int n_blocks = (NB*NPT)/32;                        // 1024

    if (ws_size >= ft_bytes + pt_bytes + tbs_bytes) {
        unsigned short* ft  = (unsigned short*)d_ws;
        float4*         pt  = (float4*)((char*)d_ws + ft_bytes);
        unsigned short* tbs = (unsigned short*)((char*)d_ws + ft_bytes + pt_bytes);
        k_prep<<<648, 256, 0, stream>>>(feat, pos, theta, pbias, ft, pt, tbs);
        k_main<true><<<n_blocks, 256, 0, stream>>>(feat, pos, nbr, theta, pbias, fbias,
                                                   ft, pt, tbs, out);
    } else {
        k_main<false><<<n_blocks, 256, 0, stream>>>(feat, pos, nbr, theta, pbias, fbias,
                                                    (const unsigned short*)feat,
                                                    (const float4*)feat,
                                                    (const unsigned short*)feat, out);
    }
}

// Round 12
// 82.214 us; speedup vs baseline: 1.0534x; 1.0534x over previous
//
#include <hip/hip_runtime.h>

#define NB    4
#define DIN_  64
#define DOUT_ 64
#define KN    16
#define NPT   8192
#define CPAD  264   // 256 c-entries + 8 pad shorts; rows 528B (16B-aligned)

typedef __attribute__((ext_vector_type(8))) short short8;
typedef __attribute__((ext_vector_type(4))) float v4f;

__device__ __forceinline__ float bf2f(unsigned short u) {
    unsigned int x = ((unsigned int)u) << 16;
    float f; __builtin_memcpy(&f, &x, 4); return f;
}
__device__ __forceinline__ unsigned short f2bf(float f) {
    unsigned int x; __builtin_memcpy(&x, &f, 4);
    x += 0x7fffu + ((x >> 16) & 1u);   // RNE
    return (unsigned short)(x >> 16);
}

// ---------- prep: 3 jobs in one dispatch (R8-exact) ----------
// blocks [0,512):  feat fp32 [B][64][N] -> ft bf16 [B][N][64]
// blocks [512,640): pos fp32 [B][3][N]  -> pt float4 (x,y,z,1)
// blocks [640,648): theta/pbias -> tbs bf16, epilogue-lane-order swizzled:
//   tbs[((w*8+ks)*64 + lane)*8 + j] = T[orow=w*16+(lane&15)][c=ks*32+(lane>>4)*8+j]
__global__ void k_prep(const float* __restrict__ feat, const float* __restrict__ pos,
                       const float* __restrict__ theta, const float* __restrict__ pbias,
                       unsigned short* __restrict__ ft, float4* __restrict__ pt,
                       unsigned short* __restrict__ tbs) {
    __shared__ float tile[64][65];
    const int bid = blockIdx.x;
    if (bid < 512) {
        int b = bid >> 7, n0 = (bid & 127) << 6;
        int lane = threadIdx.x & 63, w = threadIdx.x >> 6;
#pragma unroll
        for (int r = 0; r < 16; ++r) {
            int i = (r << 2) | w;
            tile[i][lane] = feat[(b*DIN_ + i)*NPT + n0 + lane];
        }
        __syncthreads();
#pragma unroll
        for (int r = 0; r < 16; ++r) {
            int n = (r << 2) | w;
            ft[((size_t)(b*NPT + n0 + n))*DIN_ + lane] = f2bf(tile[lane][n]);
        }
    } else if (bid < 640) {
        int t = (bid - 512)*256 + threadIdx.x;   // 0..32767
        int b = t >> 13, n = t & 8191;
        float4 v;
        v.x = pos[(b*3 + 0)*NPT + n];
        v.y = pos[(b*3 + 1)*NPT + n];
        v.z = pos[(b*3 + 2)*NPT + n];
        v.w = 1.0f;
        pt[t] = v;
    } else {
        int e = (bid - 640)*256 + threadIdx.x;   // 0..2047 = [w][ks][lane]
        int w  = e >> 9;
        int ks = (e >> 6) & 7;
        int ln = e & 63;
        int orow = (w << 4) + (ln & 15);
        int koff = (ks << 5) + ((ln >> 4) << 3);
        short8 u;
#pragma unroll
        for (int j = 0; j < 8; ++j) {
            int c = koff + j;
            float v = (c < 192) ? theta[c*64 + orow] : pbias[(c - 192)*64 + orow];
            u[j] = (short)f2bf(v);
        }
        *reinterpret_cast<short8*>(tbs + (size_t)e*8) = u;   // 16B aligned
    }
}

// ---------- main: R8-exact + non-temporal out stores ----------
// NT stores keep the 8MB out stream from evicting ft/pt gather-hot lines in
// per-XCD L2 (working set 4.5MB vs 4MB L2 -> at the eviction edge) for the
// later blocks still running stage 1 on the same CU.
template<bool USE_WS>
__global__ __launch_bounds__(256, 4) void k_main(
    const float*          __restrict__ feat,
    const float*          __restrict__ pos,
    const int*            __restrict__ nbr,
    const float*          __restrict__ theta,
    const float*          __restrict__ pbias,
    const float*          __restrict__ fbias,
    const unsigned short* __restrict__ ft,
    const float4*         __restrict__ pt,
    const unsigned short* __restrict__ tbs,
    float*                __restrict__ out)
{
    __shared__ __align__(16) unsigned short Xt[32*CPAD];  // 16896 B  [q][c]
    __shared__ int    nbs[KN*32];                         // 2048 B   [k][q]
    __shared__ float4 pcs[32];                            // 512 B
    __shared__ float4 ptk[32][16];                        // 8192 B   [q][k]
    __shared__ __align__(16) float out_s[64][32];         // 8192 B   [o][n]
    // total 35840 B -> 4 blocks/CU

    const int tid  = threadIdx.x;
    const int lane = tid & 63;
    const int w    = tid >> 6;
    const int j16  = lane & 15;
    const int pt2  = lane >> 4;    // stage1: which of 4 points; epilogue: quad (kg)

    const int base = blockIdx.x << 5;   // 32 points/block; 8192%32==0 -> single batch
    const int b    = base >> 13;
    const int nb0  = base & 8191;

    // ---- cooperative preamble: nbr slab + center positions ----
#pragma unroll
    for (int r = 0; r < 2; ++r) {
        int idx = tid + (r << 8);            // 0..511
        int k = idx >> 5, c = idx & 31;
        nbs[idx] = nbr[(b*KN + k)*NPT + nb0 + c];
    }
    if (tid < 128) {
        if (USE_WS) {
            ((float*)pcs)[tid] = ((const float*)(pt + b*NPT + nb0))[tid];
        } else if (tid < 32) {
            int n = nb0 + tid;
            pcs[tid] = make_float4(pos[(b*3+0)*NPT + n], pos[(b*3+1)*NPT + n],
                                   pos[(b*3+2)*NPT + n], 1.0f);
        }
    }
    __syncthreads();

    const unsigned short* ftb = ft + (((size_t)b) << 19);   // b*NPT*64
    const float4*         ptb = pt + b*NPT;

    // ---- stage 1: 2 passes x 4 points per wave; lane owns (point, 4-feature chunk) ----
#pragma unroll
    for (int pass = 0; pass < 2; ++pass) {
        const int q = (w << 3) + (pass << 2) + pt2;
        const float4 pc = pcs[q];

        float acc[4][4];
#pragma unroll
        for (int p = 0; p < 4; ++p)
#pragma unroll
            for (int j = 0; j < 4; ++j) acc[p][j] = 0.f;

        if (USE_WS) {
            // pt dedup (R6): lane (pt2 -> q, j16 -> k) loads pt once.
            const int idp = nbs[(j16 << 5) + q];
            ptk[q][j16] = ptb[idp];

            // depth-16 gather pipeline (R7): all ft loads issued before any FMA.
            ushort4 frA[8], frB[8];
#pragma unroll
            for (int k = 0; k < 8; ++k) {
                const int id = nbs[(k << 5) + q];
                frA[k] = *reinterpret_cast<const ushort4*>(
                    ftb + (((size_t)id) << 6) + (j16 << 2));
            }
#pragma unroll
            for (int k = 0; k < 8; ++k) {
                const int id = nbs[((k + 8) << 5) + q];
                frB[k] = *reinterpret_cast<const ushort4*>(
                    ftb + (((size_t)id) << 6) + (j16 << 2));
            }
#pragma unroll
            for (int k = 0; k < 8; ++k) {
                const float4 pg = ptk[q][k];
                float f[4] = { bf2f(frA[k].x), bf2f(frA[k].y),
                               bf2f(frA[k].z), bf2f(frA[k].w) };
#pragma unroll
                for (int j = 0; j < 4; ++j) {
                    acc[0][j] += pg.x * f[j];
                    acc[1][j] += pg.y * f[j];
                    acc[2][j] += pg.z * f[j];
                    acc[3][j] += f[j];
                }
            }
#pragma unroll
            for (int k = 0; k < 8; ++k) {
                const float4 pg = ptk[q][k + 8];
                float f[4] = { bf2f(frB[k].x), bf2f(frB[k].y),
                               bf2f(frB[k].z), bf2f(frB[k].w) };
#pragma unroll
                for (int j = 0; j < 4; ++j) {
                    acc[0][j] += pg.x * f[j];
                    acc[1][j] += pg.y * f[j];
                    acc[2][j] += pg.z * f[j];
                    acc[3][j] += f[j];
                }
            }
        } else {
#pragma unroll 4
            for (int k = 0; k < KN; ++k) {
                const int id = nbs[(k << 5) + q];
                float4 pg; float f[4];
                pg.x = pos[(b*3+0)*NPT + id];
                pg.y = pos[(b*3+1)*NPT + id];
                pg.z = pos[(b*3+2)*NPT + id];
                pg.w = 1.0f;
#pragma unroll
                for (int j = 0; j < 4; ++j)
                    f[j] = feat[(b*DIN_ + (j16<<2) + j)*NPT + id];
#pragma unroll
                for (int j = 0; j < 4; ++j) {
                    acc[0][j] += pg.x * f[j];
                    acc[1][j] += pg.y * f[j];
                    acc[2][j] += pg.z * f[j];
                    acc[3][j] += f[j];
                }
            }
        }
        // center correction: M_p -= pc_p * S
#pragma unroll
        for (int j = 0; j < 4; ++j) {
            acc[0][j] -= pc.x * acc[3][j];
            acc[1][j] -= pc.y * acc[3][j];
            acc[2][j] -= pc.z * acc[3][j];
        }
        // write X[q][c], c = p*64 + j16*4 + j  (bf16)
#pragma unroll
        for (int p = 0; p < 4; ++p) {
            ushort4 pk;
            pk.x = f2bf(acc[p][0]); pk.y = f2bf(acc[p][1]);
            pk.z = f2bf(acc[p][2]); pk.w = f2bf(acc[p][3]);
            *reinterpret_cast<ushort4*>(&Xt[q*CPAD + (p<<6) + (j16<<2)]) = pk;
        }
    }
    __syncthreads();

    // ---- epilogue: wave w -> o-rows [16w,16w+16); A-frags from swizzled tbs ----
    const int kg   = pt2;                 // mfma quad
    const int orow = (w << 4) + j16;      // A: m = lane&15
    v4f acc0 = {0.f,0.f,0.f,0.f}, acc1 = {0.f,0.f,0.f,0.f};
#pragma unroll
    for (int ks = 0; ks < 8; ++ks) {
        const int koff = (ks << 5) + (kg << 3);   // k = quad*8 + j
        short8 a;
        if (USE_WS) {
            // contiguous: 64 lanes x 16B = 1KB segment per inst
            a = *reinterpret_cast<const short8*>(
                tbs + ((size_t)(((w << 3) + ks) << 6) + lane) * 8);
        } else {
#pragma unroll
            for (int j = 0; j < 8; ++j) {
                int c = koff + j;
                float v = (c < 192) ? theta[c*64 + orow] : pbias[(c - 192)*64 + orow];
                a[j] = (short)f2bf(v);
            }
        }
        short8 b0 = *reinterpret_cast<const short8*>(&Xt[j16*CPAD + koff]);
        short8 b1 = *reinterpret_cast<const short8*>(&Xt[(16 + j16)*CPAD + koff]);
        acc0 = __builtin_amdgcn_mfma_f32_16x16x32_bf16(a, b0, acc0, 0, 0, 0);
        acc1 = __builtin_amdgcn_mfma_f32_16x16x32_bf16(a, b1, acc1, 0, 0, 0);
    }
    // C/D: col=lane&15 (point), row=quad*4+reg (o). Stage to LDS, then write
    // FULL 128B lines (one o-row's 32 floats = one cache line) -> no RFO.
#pragma unroll
    for (int r = 0; r < 4; ++r) {
        const int o = (w << 4) + (kg << 2) + r;
        const float fb = fbias[o];
        out_s[o][j16]      = acc0[r] + fb;
        out_s[o][16 + j16] = acc1[r] + fb;
    }
    __syncthreads();
#pragma unroll
    for (int rep = 0; rep < 2; ++rep) {
        const int c  = tid + (rep << 8);     // 0..511 float4-chunks
        const int o  = c >> 3, seg = c & 7;
        const v4f v = *reinterpret_cast<const v4f*>(&out_s[o][seg << 2]);
        // non-temporal: don't let the out stream evict ft/pt from L2.
        // (ext_vector type v4f, not HIP_vector_type float4 — builtin requires it)
        __builtin_nontemporal_store(v, reinterpret_cast<v4f*>(
            &out[(size_t)(b*DOUT_ + o)*NPT + nb0 + (seg << 2)]));
    }
}

extern "C" void kernel_launch(void* const* d_in, const int* in_sizes, int n_in,
                              void* d_out, int out_size, void* d_ws, size_t ws_size,
                              hipStream_t stream) {
    const float* feat  = (const float*)d_in[0];
    const float* pos   = (const float*)d_in[1];
    const int*   nbr   = (const int*)d_in[2];
    const float* theta = (const float*)d_in[3];
    const float* pbias = (const float*)d_in[4];
    const float* fbias = (const float*)d_in[5];
    float* out = (float*)d_out;

    const size_t ft_bytes  = (size_t)NB*NPT*DIN_*2;          // 4 MiB
    const size_t pt_bytes  = (size_t)NB*NPT*sizeof(float4);  // 512 KiB
    const size_t tbs_bytes = (size_t)DOUT_*256*2;            // 32 KiB
    const int n_blocks = (NB*NPT)/32;                        // 1024

    if (ws_size >= ft_bytes + pt_bytes + tbs_bytes) {
        unsigned short* ft  = (unsigned short*)d_ws;
        float4*         pt  = (float4*)((char*)d_ws + ft_bytes);
        unsigned short* tbs = (unsigned short*)((char*)d_ws + ft_bytes + pt_bytes);
        k_prep<<<648, 256, 0, stream>>>(feat, pos, theta, pbias, ft, pt, tbs);
        k_main<true><<<n_blocks, 256, 0, stream>>>(feat, pos, nbr, theta, pbias, fbias,
                                                   ft, pt, tbs, out);
    } else {
        k_main<false><<<n_blocks, 256, 0, stream>>>(feat, pos, nbr, theta, pbias, fbias,
                                                    (const unsigned short*)feat,
                                                    (const float4*)feat,
                                                    (const unsigned short*)feat, out);
    }
}